// Round 2
// baseline (500.575 us; speedup 1.0000x reference)
//
#include <hip/hip_runtime.h>
#include <hip/hip_bf16.h>
#include <math.h>

// Problem constants: B=4, T=2048, C=1024, H=16, D=64
#define B_   4
#define T_   2048
#define C_   1024
#define H_   16
#define D_   64
#define M_   (B_*T_)   // 8192 rows
#define N3   (3*C_)    // 3072
#define KDIM C_        // 1024

typedef __attribute__((ext_vector_type(8))) short bf16x8;   // 8 bf16 = 4 VGPR (MFMA A/B frag)
typedef __attribute__((ext_vector_type(4))) float f32x4;    // MFMA C/D frag

#define MFMA16(a,b,c) __builtin_amdgcn_mfma_f32_16x16x32_bf16(a,b,c,0,0,0)

// 1/sqrt(64) * log2(e): folded into Q so softmax uses exp2 directly
#define QSCALE 0.18033688011112042f

__device__ __forceinline__ unsigned short f2bf(float f) {
  union { float f; unsigned u; } a; a.f = f;
  unsigned r = a.u + 0x7fffu + ((a.u >> 16) & 1u);   // RNE (inputs are finite)
  return (unsigned short)(r >> 16);
}

__device__ __forceinline__ void gload16(const void* g, void* l) {
  // async global->LDS, 16B per lane; LDS dest = wave-uniform base + lane*16
  __builtin_amdgcn_global_load_lds(
      (const __attribute__((address_space(1))) void*)g,
      (__attribute__((address_space(3))) void*)l, 16, 0, 0);
}

// ---------------- cast x (f32 -> bf16), 4 elems/thread ----------------
__global__ void cast_f32_bf16(const float* __restrict__ in,
                              unsigned short* __restrict__ out, int n) {
  int i = (blockIdx.x * 256 + threadIdx.x) * 4;
  if (i >= n) return;
  float4 v = *(const float4*)(in + i);
  ushort4 o;
  o.x = f2bf(v.x); o.y = f2bf(v.y); o.z = f2bf(v.z); o.w = f2bf(v.w);
  *(ushort4*)(out + i) = o;
}

// -------- transpose + cast: in[R][Ncols] f32 -> out[Ncols][R] bf16 --------
__global__ void transpose_cast(const float* __restrict__ in,
                               unsigned short* __restrict__ out,
                               int R, int Ncols) {
  __shared__ float tile[32][33];           // +1 pad: no bank conflicts
  int bc = blockIdx.x * 32;                // col base (Ncols dim)
  int br = blockIdx.y * 32;                // row base (R dim)
  int tx = threadIdx.x, ty = threadIdx.y;  // 32 x 8
  #pragma unroll
  for (int i = ty; i < 32; i += 8)
    tile[i][tx] = in[(size_t)(br + i) * Ncols + bc + tx];
  __syncthreads();
  #pragma unroll
  for (int i = ty; i < 32; i += 8)
    out[(size_t)(bc + i) * R + br + tx] = f2bf(tile[tx][i]);
}

// ---------------- 128x128x64 bf16 MFMA GEMM, Bt = B transposed [N][K] ------
// MODE 0: QKV epilogue -> q (scaled QSCALE), k, vT scatter (bf16)
// MODE 1: plain f32 C write (proj)
template<int MODE>
__global__ __launch_bounds__(256)
void gemm128(const unsigned short* __restrict__ A,    // [M][K] bf16
             const unsigned short* __restrict__ Bt,   // [N][K] bf16
             unsigned short* __restrict__ qo,
             unsigned short* __restrict__ ko,
             unsigned short* __restrict__ vto,
             float* __restrict__ outf) {
  __shared__ short Asl[128 * 64];   // [m 128][k 64], 16KB
  __shared__ short Bsl[128 * 64];   // [n 128][k 64], 16KB
  const int tid  = threadIdx.x;
  const int wid  = tid >> 6, lane = tid & 63;
  const int l15  = lane & 15, l4 = lane >> 4;
  const int tm   = blockIdx.y * 128;
  const int tn   = blockIdx.x * 128;
  const int wm   = (wid >> 1) * 64, wn = (wid & 1) * 64;

  f32x4 acc[4][4] = {};

  const int stoff = wid * 1024 + lane * 16;   // this thread's byte slot per round

  for (int kt = 0; kt < KDIM; kt += 64) {
    __syncthreads();   // previous compute done before overwriting LDS
    #pragma unroll
    for (int ro = 0; ro < 4; ++ro) {
      int off = ro * 4096 + stoff;
      int row = off >> 7;              // 128B per LDS row (64 bf16)
      int ce  = (off & 127) >> 1;      // elem within row
      gload16(A  + (size_t)(tm + row) * KDIM + kt + ce,
              (char*)Asl + ro * 4096 + wid * 1024);
      gload16(Bt + (size_t)(tn + row) * KDIM + kt + ce,
              (char*)Bsl + ro * 4096 + wid * 1024);
    }
    __syncthreads();   // compiler drains vmcnt before s_barrier -> tiles ready

    #pragma unroll
    for (int ks = 0; ks < 2; ++ks) {
      bf16x8 af[4], bfr[4];
      #pragma unroll
      for (int i = 0; i < 4; ++i) {
        af[i]  = *(const bf16x8*)&Asl[(wm + i*16 + l15) * 64 + ks*32 + l4*8];
        bfr[i] = *(const bf16x8*)&Bsl[(wn + i*16 + l15) * 64 + ks*32 + l4*8];
      }
      #pragma unroll
      for (int mi = 0; mi < 4; ++mi)
        #pragma unroll
        for (int ni = 0; ni < 4; ++ni)
          acc[mi][ni] = MFMA16(af[mi], bfr[ni], acc[mi][ni]);
    }
  }

  // epilogue: D[row][col], col = lane&15, row = (lane>>4)*4 + r  [measured m89/m91]
  #pragma unroll
  for (int mi = 0; mi < 4; ++mi) {
    #pragma unroll
    for (int ni = 0; ni < 4; ++ni) {
      #pragma unroll
      for (int r = 0; r < 4; ++r) {
        int m = tm + wm + mi*16 + l4*4 + r;
        int n = tn + wn + ni*16 + l15;
        float val = acc[mi][ni][r];
        if (MODE == 0) {
          int b = m >> 11, t = m & (T_ - 1);
          int which = n >> 10, n1 = n & (C_ - 1);
          int h = n1 >> 6, d = n1 & 63;
          size_t bh = (size_t)(b * H_ + h);
          if (which == 0)      qo[(bh * T_ + t) * D_ + d] = f2bf(val * QSCALE); // fold 1/sqrt(D)*log2e
          else if (which == 1) ko[(bh * T_ + t) * D_ + d] = f2bf(val);
          else                 vto[(bh * D_ + d) * T_ + t] = f2bf(val);          // V transposed
        } else {
          outf[(size_t)m * C_ + n] = val;
        }
      }
    }
  }
}

// ---------------- causal flash attention (swapped-QK, lane-local softmax) --
// grid (64 bh, 32 qtiles rev), block 256 = 4 independent waves, 16 q-rows/wave
__global__ __launch_bounds__(256)
void attn64(const unsigned short* __restrict__ Q,    // [BH][T][D], pre-scaled
            const unsigned short* __restrict__ K,    // [BH][T][D]
            const unsigned short* __restrict__ Vt,   // [BH][D][T]
            unsigned short* __restrict__ Y) {        // [B][T][C] bf16
  // per-wave P buffer: 16 rows x 64 cols bf16 (2KB), XOR-swizzled
  __shared__ short P_lds[4][16 * 64];
  const int bh  = blockIdx.x;
  const int qt  = (int)gridDim.y - 1 - (int)blockIdx.y;  // heavy tiles first
  const int tid = threadIdx.x, wid = tid >> 6, lane = tid & 63;
  const int l15 = lane & 15, l4 = lane >> 4;
  const int q0  = qt * 64 + wid * 16;                    // wave's q rows
  const int b   = bh >> 4, h = bh & 15;

  const unsigned short* Qp = Q  + (size_t)bh * T_ * D_;
  const unsigned short* Kp = K  + (size_t)bh * T_ * D_;
  const unsigned short* Vp = Vt + (size_t)bh * D_ * T_;

  // Q fragment (second operand of swapped QK): l15 = q-row
  bf16x8 qf[2];
  #pragma unroll
  for (int c = 0; c < 2; ++c)
    qf[c] = *(const bf16x8*)&Qp[(q0 + l15) * D_ + c*32 + l4*8];

  f32x4 yacc[4] = {};                    // Y rows q=l4*4+r, cols d=di*16+l15
  float m_q = -INFINITY;                 // softmax state for q = q0 + l15
  float l_q = 0.f;
  char* pl = (char*)&P_lds[wid][0];

  // swizzle helper: row-major [16][64] bf16, byte ^= (row&7)<<4  [G4 recipe]
  #define PSWZ(rowv, bytecol) ((((rowv) * 128 + (bytecol)) ^ (((rowv) & 7) << 4)))

  for (int kt = 0; kt <= qt; ++kt) {
    const int k0 = kt * 64;

    // ---- prefetch V fragments (independent; hides L2 latency under softmax)
    bf16x8 vfr[4][2];
    #pragma unroll
    for (int di = 0; di < 4; ++di)
      #pragma unroll
      for (int c = 0; c < 2; ++c)
        vfr[di][c] = *(const bf16x8*)&Vp[(size_t)(di*16 + l15) * T_ + k0 + c*32 + l4*8];

    // ---- S = K Q^T (swapped): s2[ksub][r] = S[k = k0+ksub*16+l4*4+r][q = q0+l15]
    f32x4 s2[4];
    __builtin_amdgcn_s_setprio(1);
    #pragma unroll
    for (int ksub = 0; ksub < 4; ++ksub) {
      f32x4 a = {0.f, 0.f, 0.f, 0.f};
      #pragma unroll
      for (int c = 0; c < 2; ++c) {
        bf16x8 kf = *(const bf16x8*)&Kp[(size_t)(k0 + ksub*16 + l15) * D_ + c*32 + l4*8];
        a = MFMA16(kf, qf[c], a);
      }
      s2[ksub] = a;
    }
    __builtin_amdgcn_s_setprio(0);

    if (kt == qt) {   // diagonal tile: mask k > q (both lane-local)
      #pragma unroll
      for (int ksub = 0; ksub < 4; ++ksub)
        #pragma unroll
        for (int r = 0; r < 4; ++r)
          if (k0 + ksub*16 + l4*4 + r > q0 + l15) s2[ksub][r] = -INFINITY;
    }

    // ---- online softmax, lane-local for q = q0+l15 (S already in log2 units)
    float tmax = s2[0][0];
    #pragma unroll
    for (int ksub = 0; ksub < 4; ++ksub)
      #pragma unroll
      for (int r = 0; r < 4; ++r) tmax = fmaxf(tmax, s2[ksub][r]);
    tmax = fmaxf(tmax, __shfl_xor(tmax, 16, 64));
    tmax = fmaxf(tmax, __shfl_xor(tmax, 32, 64));
    float mn = fmaxf(m_q, tmax);
    float scale_q = exp2f(m_q - mn);
    m_q = mn;

    float rsum = 0.f;
    #pragma unroll
    for (int ksub = 0; ksub < 4; ++ksub)
      #pragma unroll
      for (int r = 0; r < 4; ++r) {
        float p = exp2f(s2[ksub][r] - mn);
        s2[ksub][r] = p;
        rsum += p;
      }
    rsum += __shfl_xor(rsum, 16, 64);
    rsum += __shfl_xor(rsum, 32, 64);
    l_q = l_q * scale_q + rsum;

    // broadcast scale to yacc layout (row q = q0 + l4*4 + r lives at lane l4*4+r)
    #pragma unroll
    for (int r = 0; r < 4; ++r) {
      float sc = __shfl(scale_q, (l4 << 2) | r, 64);
      #pragma unroll
      for (int di = 0; di < 4; ++di) yacc[di][r] *= sc;
    }

    // ---- P (bf16) -> LDS [q-row][k-col], swizzled vector writes
    asm volatile("s_waitcnt lgkmcnt(0)" ::: "memory");  // prior P reads done
    __builtin_amdgcn_sched_barrier(0);
    #pragma unroll
    for (int ksub = 0; ksub < 4; ++ksub) {
      ushort4 w;
      w.x = f2bf(s2[ksub][0]); w.y = f2bf(s2[ksub][1]);
      w.z = f2bf(s2[ksub][2]); w.w = f2bf(s2[ksub][3]);
      *(ushort4*)(pl + PSWZ(l15, ksub*32 + l4*8)) = w;   // k = ksub*16+l4*4+{0..3}
    }
    asm volatile("s_waitcnt lgkmcnt(0)" ::: "memory");  // writes visible (same wave)
    __builtin_amdgcn_sched_barrier(0);

    // ---- read P as A-frag: lane holds P[q=l15][k = ks*32 + l4*8 + 0..7]
    bf16x8 pf[2];
    #pragma unroll
    for (int ks = 0; ks < 2; ++ks)
      pf[ks] = *(const bf16x8*)(pl + PSWZ(l15, ks*64 + l4*16));
    asm volatile("s_waitcnt lgkmcnt(0)" ::: "memory");
    __builtin_amdgcn_sched_barrier(0);

    // ---- Y += P V
    __builtin_amdgcn_s_setprio(1);
    #pragma unroll
    for (int di = 0; di < 4; ++di)
      #pragma unroll
      for (int ks = 0; ks < 2; ++ks)
        yacc[di] = MFMA16(pf[ks], vfr[di][ks], yacc[di]);
    __builtin_amdgcn_s_setprio(0);
  }

  // ---- epilogue: divide by l (held at lane l4*4+r), store bf16
  #pragma unroll
  for (int r = 0; r < 4; ++r) {
    float lr = __shfl(l_q, (l4 << 2) | r, 64);
    float inv = 1.0f / lr;
    int t = q0 + l4*4 + r;
    #pragma unroll
    for (int di = 0; di < 4; ++di) {
      int d = di*16 + l15;
      Y[((size_t)b * T_ + t) * C_ + h * D_ + d] = f2bf(yacc[di][r] * inv);
    }
  }
  #undef PSWZ
}

// ---------------------------------------------------------------------------
extern "C" void kernel_launch(void* const* d_in, const int* in_sizes, int n_in,
                              void* d_out, int out_size, void* d_ws, size_t ws_size,
                              hipStream_t stream) {
  const float* x      = (const float*)d_in[0];
  const float* w_attn = (const float*)d_in[1];
  const float* w_proj = (const float*)d_in[2];
  float* out = (float*)d_out;

  char* ws = (char*)d_ws;
  size_t off = 0;
  auto alloc = [&](size_t bytes) {
    char* p = ws + off; off += (bytes + 255) & ~(size_t)255; return p;
  };
  unsigned short* xb  = (unsigned short*)alloc((size_t)M_ * C_ * 2);  // x bf16
  unsigned short* wat = (unsigned short*)alloc((size_t)N3 * KDIM * 2);// w_attn^T bf16
  unsigned short* wpt = (unsigned short*)alloc((size_t)C_ * C_ * 2);  // w_proj^T bf16
  unsigned short* qb  = (unsigned short*)alloc((size_t)M_ * C_ * 2);  // Q [BH][T][D]
  unsigned short* kb  = (unsigned short*)alloc((size_t)M_ * C_ * 2);  // K [BH][T][D]
  unsigned short* vtb = (unsigned short*)alloc((size_t)M_ * C_ * 2);  // V^T [BH][D][T]
  unsigned short* yb  = (unsigned short*)alloc((size_t)M_ * C_ * 2);  // attn out bf16

  cast_f32_bf16<<<dim3(M_ * C_ / 1024), dim3(256), 0, stream>>>(x, xb, M_ * C_);
  transpose_cast<<<dim3(N3 / 32, KDIM / 32), dim3(32, 8), 0, stream>>>(w_attn, wat, KDIM, N3);
  transpose_cast<<<dim3(C_ / 32, C_ / 32), dim3(32, 8), 0, stream>>>(w_proj, wpt, C_, C_);

  gemm128<0><<<dim3(N3 / 128, M_ / 128), dim3(256), 0, stream>>>(xb, wat, qb, kb, vtb, nullptr);
  attn64<<<dim3(B_ * H_, T_ / 64), dim3(256), 0, stream>>>(qb, kb, vtb, yb);
  gemm128<1><<<dim3(C_ / 128, M_ / 128), dim3(256), 0, stream>>>(yb, wpt, nullptr, nullptr, nullptr, out);
}

// Round 4
// 354.027 us; speedup vs baseline: 1.4139x; 1.4139x over previous
//
#include <hip/hip_runtime.h>
#include <hip/hip_bf16.h>
#include <math.h>

// Problem constants: B=4, T=2048, C=1024, H=16, D=64
#define B_   4
#define T_   2048
#define C_   1024
#define H_   16
#define D_   64
#define M_   (B_*T_)   // 8192 rows
#define N3   (3*C_)    // 3072
#define KDIM C_        // 1024

typedef __attribute__((ext_vector_type(8)))  short bf16x8;   // MFMA A/B frag (4 VGPR)
typedef __attribute__((ext_vector_type(4)))  float f32x4;    // 16x16 C/D frag
typedef __attribute__((ext_vector_type(16))) float f32x16;   // 32x32 C/D frag
typedef __attribute__((ext_vector_type(4)))  unsigned int u32x4;

#define MFMA16(a,b,c) __builtin_amdgcn_mfma_f32_16x16x32_bf16(a,b,c,0,0,0)
#define MFMA32(a,b,c) __builtin_amdgcn_mfma_f32_32x32x16_bf16(a,b,c,0,0,0)

// 1/sqrt(64) * log2(e): folded into Q so softmax uses exp2 directly
#define QSCALE 0.18033688011112042f

__device__ __forceinline__ unsigned short f2bf(float f) {
  union { float f; unsigned u; } a; a.f = f;
  unsigned r = a.u + 0x7fffu + ((a.u >> 16) & 1u);   // RNE (inputs are finite)
  return (unsigned short)(r >> 16);
}

// packed RNE f32x2 -> bf16x2 (T12 recipe: no builtin on gfx950, use asm)
__device__ __forceinline__ unsigned cvtpk(float lo, float hi) {
  unsigned r;
  asm("v_cvt_pk_bf16_f32 %0, %1, %2" : "=v"(r) : "v"(lo), "v"(hi));
  return r;
}

__device__ __forceinline__ void gload16(const void* g, void* l) {
  __builtin_amdgcn_global_load_lds(
      (const __attribute__((address_space(1))) void*)g,
      (__attribute__((address_space(3))) void*)l, 16, 0, 0);
}

// ---------------- cast x (f32 -> bf16), 4 elems/thread ----------------
__global__ void cast_f32_bf16(const float* __restrict__ in,
                              unsigned short* __restrict__ out, int n) {
  int i = (blockIdx.x * 256 + threadIdx.x) * 4;
  if (i >= n) return;
  float4 v = *(const float4*)(in + i);
  ushort4 o;
  o.x = f2bf(v.x); o.y = f2bf(v.y); o.z = f2bf(v.z); o.w = f2bf(v.w);
  *(ushort4*)(out + i) = o;
}

// -------- transpose + cast: in[R][Ncols] f32 -> out[Ncols][R] bf16 --------
__global__ void transpose_cast(const float* __restrict__ in,
                               unsigned short* __restrict__ out,
                               int R, int Ncols) {
  __shared__ float tile[32][33];
  int bc = blockIdx.x * 32;
  int br = blockIdx.y * 32;
  int tx = threadIdx.x, ty = threadIdx.y;  // 32 x 8
  #pragma unroll
  for (int i = ty; i < 32; i += 8)
    tile[i][tx] = in[(size_t)(br + i) * Ncols + bc + tx];
  __syncthreads();
  #pragma unroll
  for (int i = ty; i < 32; i += 8)
    out[(size_t)(bc + i) * R + br + tx] = f2bf(tile[tx][i]);
}

// ---------------- 128x128x64 bf16 MFMA GEMM, Bt = B transposed [N][K] ------
template<int MODE>
__global__ __launch_bounds__(256)
void gemm128(const unsigned short* __restrict__ A,    // [M][K] bf16
             const unsigned short* __restrict__ Bt,   // [N][K] bf16
             unsigned short* __restrict__ qo,
             unsigned short* __restrict__ ko,
             unsigned short* __restrict__ vto,
             float* __restrict__ outf) {
  __shared__ short Asl[128 * 64];
  __shared__ short Bsl[128 * 64];
  const int tid  = threadIdx.x;
  const int wid  = tid >> 6, lane = tid & 63;
  const int l15  = lane & 15, l4 = lane >> 4;
  const int tm   = blockIdx.y * 128;
  const int tn   = blockIdx.x * 128;
  const int wm   = (wid >> 1) * 64, wn = (wid & 1) * 64;

  f32x4 acc[4][4] = {};
  const int stoff = wid * 1024 + lane * 16;

  for (int kt = 0; kt < KDIM; kt += 64) {
    __syncthreads();
    #pragma unroll
    for (int ro = 0; ro < 4; ++ro) {
      int off = ro * 4096 + stoff;
      int row = off >> 7;
      int ce  = (off & 127) >> 1;
      gload16(A  + (size_t)(tm + row) * KDIM + kt + ce,
              (char*)Asl + ro * 4096 + wid * 1024);
      gload16(Bt + (size_t)(tn + row) * KDIM + kt + ce,
              (char*)Bsl + ro * 4096 + wid * 1024);
    }
    __syncthreads();

    #pragma unroll
    for (int ks = 0; ks < 2; ++ks) {
      bf16x8 af[4], bfr[4];
      #pragma unroll
      for (int i = 0; i < 4; ++i) {
        af[i]  = *(const bf16x8*)&Asl[(wm + i*16 + l15) * 64 + ks*32 + l4*8];
        bfr[i] = *(const bf16x8*)&Bsl[(wn + i*16 + l15) * 64 + ks*32 + l4*8];
      }
      #pragma unroll
      for (int mi = 0; mi < 4; ++mi)
        #pragma unroll
        for (int ni = 0; ni < 4; ++ni)
          acc[mi][ni] = MFMA16(af[mi], bfr[ni], acc[mi][ni]);
    }
  }

  #pragma unroll
  for (int mi = 0; mi < 4; ++mi) {
    #pragma unroll
    for (int ni = 0; ni < 4; ++ni) {
      #pragma unroll
      for (int r = 0; r < 4; ++r) {
        int m = tm + wm + mi*16 + l4*4 + r;
        int n = tn + wn + ni*16 + l15;
        float val = acc[mi][ni][r];
        if (MODE == 0) {
          int b = m >> 11, t = m & (T_ - 1);
          int which = n >> 10, n1 = n & (C_ - 1);
          int h = n1 >> 6, d = n1 & 63;
          size_t bh = (size_t)(b * H_ + h);
          if (which == 0)      qo[(bh * T_ + t) * D_ + d] = f2bf(val * QSCALE);
          else if (which == 1) ko[(bh * T_ + t) * D_ + d] = f2bf(val);
          else                 vto[(bh * D_ + d) * T_ + t] = f2bf(val);
        } else {
          outf[(size_t)m * C_ + n] = val;
        }
      }
    }
  }
}

// ---------------- causal flash attention: 32x32 all-in-register ------------
// grid (64 bh, 16 qblocks rev), block 256 = 4 independent waves, 32 q-rows/wave
// Swapped QK^T AND swapped PV: everything is col=q=lane&31 -> softmax state,
// rescale, and epilogue are all lane-local. No LDS, no barriers.
__global__ __launch_bounds__(256)
void attn32(const unsigned short* __restrict__ Q,    // [BH][T][D], pre-scaled
            const unsigned short* __restrict__ K,    // [BH][T][D]
            const unsigned short* __restrict__ Vt,   // [BH][D][T]
            unsigned short* __restrict__ Y) {        // [B][T][C] bf16
  const int bh   = blockIdx.x;
  const int qb   = (int)gridDim.y - 1 - (int)blockIdx.y;  // heavy blocks first
  const int lane = threadIdx.x & 63, w = threadIdx.x >> 6;
  const int l31  = lane & 31, hi = lane >> 5;
  const int q0   = qb * 128 + w * 32;                     // wave's 32 q-rows
  const int b    = bh >> 4, h = bh & 15;

  const unsigned short* Qp = Q  + (size_t)bh * T_ * D_;
  const unsigned short* Kp = K  + (size_t)bh * T_ * D_;
  const unsigned short* Vp = Vt + (size_t)bh * D_ * T_;

  // Q as B-frag (col=q=l31, contraction d = c*16 + hi*8 + j)
  bf16x8 qf[4];
  #pragma unroll
  for (int c = 0; c < 4; ++c)
    qf[c] = *(const bf16x8*)&Qp[(size_t)(q0 + l31) * D_ + c*16 + hi*8];

  f32x16 acc[2] = {};            // Y^T: col=q=l31, row d = dt*32 + crow(r,hi)
  float m_q = -INFINITY, l_q = 0.f;

  const int nt = (q0 + 31) / 64 + 1;
  for (int kt = 0; kt < nt; ++kt) {
    const int k0 = kt * 64;

    // K as A-frag (row=k=l31 within sub-tile, contraction d = c*16+hi*8+j)
    bf16x8 kf[2][4];
    #pragma unroll
    for (int kb = 0; kb < 2; ++kb)
      #pragma unroll
      for (int c = 0; c < 4; ++c)
        kf[kb][c] = *(const bf16x8*)&Kp[(size_t)(k0 + kb*32 + l31) * D_ + c*16 + hi*8];

    // S^T = K Q^T: s2[kb] col=q=l31, row k = k0+kb*32+crow(r,hi)
    f32x16 s2[2] = {};
    #pragma unroll
    for (int c = 0; c < 4; ++c) s2[0] = MFMA32(kf[0][c], qf[c], s2[0]);
    #pragma unroll
    for (int c = 0; c < 4; ++c) s2[1] = MFMA32(kf[1][c], qf[c], s2[1]);

    // V^T as A-frag for PV (row=d, contraction k): issued here, consumed after
    // softmax -> L2 latency hides under the VALU phase.
    bf16x8 va[2][4];
    #pragma unroll
    for (int dt = 0; dt < 2; ++dt)
      #pragma unroll
      for (int s = 0; s < 4; ++s)
        va[dt][s] = *(const bf16x8*)&Vp[(size_t)(dt*32 + l31) * T_ + k0 + s*16 + hi*8];

    if (kt == nt - 1) {          // diagonal: mask k > q (lane-local compare)
      #pragma unroll
      for (int kb = 0; kb < 2; ++kb)
        #pragma unroll
        for (int r = 0; r < 16; ++r) {
          int krow = k0 + kb*32 + (r&3) + 8*(r>>2) + 4*hi;
          if (krow > q0 + l31) s2[kb][r] = -INFINITY;
        }
    }

    // ---- online softmax, fully lane-local for q = q0+l31
    float tmax = s2[0][0];
    #pragma unroll
    for (int kb = 0; kb < 2; ++kb)
      #pragma unroll
      for (int r = 0; r < 16; ++r) tmax = fmaxf(tmax, s2[kb][r]);
    tmax = fmaxf(tmax, __shfl_xor(tmax, 32, 64));   // merge hi/lo k-halves
    float mn = fmaxf(m_q, tmax);
    float scale = exp2f(m_q - mn);                  // Q pre-scaled by log2e
    m_q = mn;

    float rsum = 0.f;
    #pragma unroll
    for (int kb = 0; kb < 2; ++kb)
      #pragma unroll
      for (int r = 0; r < 16; ++r) {
        float p = exp2f(s2[kb][r] - mn);
        s2[kb][r] = p;
        rsum += p;
      }
    rsum += __shfl_xor(rsum, 32, 64);
    l_q = l_q * scale + rsum;

    #pragma unroll
    for (int r = 0; r < 16; ++r) { acc[0][r] *= scale; acc[1][r] *= scale; }

    // ---- P pack (cvt_pk) + permlane32_swap -> P^T B-frags pb[s]
    // source: s2[kb][r] = P[k = kb*32 + (r&3)+8*(r>>2)+4*hi][q=l31]
    // target: pb[s] word m = P[k = s*16 + hi*8 + 2m + {0,1}][q=l31]
    u32x4 pb[4];
    #pragma unroll
    for (int kb = 0; kb < 2; ++kb)
      #pragma unroll
      for (int ss = 0; ss < 2; ++ss)
        #pragma unroll
        for (int b2 = 0; b2 < 2; ++b2) {
          unsigned ce = cvtpk(s2[kb][8*ss     + 2*b2], s2[kb][8*ss     + 2*b2 + 1]);
          unsigned co = cvtpk(s2[kb][8*ss + 4 + 2*b2], s2[kb][8*ss + 4 + 2*b2 + 1]);
          auto rr = __builtin_amdgcn_permlane32_swap(ce, co, false, false);
          pb[kb*2 + ss][b2]     = rr[0];   // {ce.lo32, co.lo32}
          pb[kb*2 + ss][2 + b2] = rr[1];   // {ce.hi32, co.hi32}
        }

    // ---- Y^T += V^T P^T
    #pragma unroll
    for (int dt = 0; dt < 2; ++dt)
      #pragma unroll
      for (int s = 0; s < 4; ++s)
        acc[dt] = MFMA32(va[dt][s], __builtin_bit_cast(bf16x8, pb[s]), acc[dt]);
  }

  // ---- epilogue: all lane-local; pack 4 consecutive d as 8B stores
  float inv = 1.0f / l_q;
  const int t = q0 + l31;
  unsigned short* Yrow = Y + ((size_t)b * T_ + t) * C_ + h * D_;
  #pragma unroll
  for (int dt = 0; dt < 2; ++dt)
    #pragma unroll
    for (int rg = 0; rg < 4; ++rg) {
      uint2 wv;
      wv.x = cvtpk(acc[dt][rg*4 + 0] * inv, acc[dt][rg*4 + 1] * inv);
      wv.y = cvtpk(acc[dt][rg*4 + 2] * inv, acc[dt][rg*4 + 3] * inv);
      *(uint2*)(Yrow + dt*32 + rg*8 + hi*4) = wv;   // d = dt*32+8rg+4hi+{0..3}
    }
}

// ---------------------------------------------------------------------------
extern "C" void kernel_launch(void* const* d_in, const int* in_sizes, int n_in,
                              void* d_out, int out_size, void* d_ws, size_t ws_size,
                              hipStream_t stream) {
  const float* x      = (const float*)d_in[0];
  const float* w_attn = (const float*)d_in[1];
  const float* w_proj = (const float*)d_in[2];
  float* out = (float*)d_out;

  char* ws = (char*)d_ws;
  size_t off = 0;
  auto alloc = [&](size_t bytes) {
    char* p = ws + off; off += (bytes + 255) & ~(size_t)255; return p;
  };
  unsigned short* xb  = (unsigned short*)alloc((size_t)M_ * C_ * 2);
  unsigned short* wat = (unsigned short*)alloc((size_t)N3 * KDIM * 2);
  unsigned short* wpt = (unsigned short*)alloc((size_t)C_ * C_ * 2);
  unsigned short* qb  = (unsigned short*)alloc((size_t)M_ * C_ * 2);
  unsigned short* kb  = (unsigned short*)alloc((size_t)M_ * C_ * 2);
  unsigned short* vtb = (unsigned short*)alloc((size_t)M_ * C_ * 2);
  unsigned short* yb  = (unsigned short*)alloc((size_t)M_ * C_ * 2);

  cast_f32_bf16<<<dim3(M_ * C_ / 1024), dim3(256), 0, stream>>>(x, xb, M_ * C_);
  transpose_cast<<<dim3(N3 / 32, KDIM / 32), dim3(32, 8), 0, stream>>>(w_attn, wat, KDIM, N3);
  transpose_cast<<<dim3(C_ / 32, C_ / 32), dim3(32, 8), 0, stream>>>(w_proj, wpt, C_, C_);

  gemm128<0><<<dim3(N3 / 128, M_ / 128), dim3(256), 0, stream>>>(xb, wat, qb, kb, vtb, nullptr);
  attn32<<<dim3(B_ * H_, T_ / 128), dim3(256), 0, stream>>>(qb, kb, vtb, yb);
  gemm128<1><<<dim3(C_ / 128, M_ / 128), dim3(256), 0, stream>>>(yb, wpt, nullptr, nullptr, nullptr, out);
}

// Round 5
// 351.621 us; speedup vs baseline: 1.4236x; 1.0068x over previous
//
#include <hip/hip_runtime.h>
#include <hip/hip_bf16.h>
#include <math.h>

// Problem constants: B=4, T=2048, C=1024, H=16, D=64
#define B_   4
#define T_   2048
#define C_   1024
#define H_   16
#define D_   64
#define M_   (B_*T_)   // 8192 rows
#define N3   (3*C_)    // 3072
#define KDIM C_        // 1024

typedef __attribute__((ext_vector_type(8)))  short bf16x8;   // MFMA A/B frag (4 VGPR)
typedef __attribute__((ext_vector_type(4)))  float f32x4;    // 16x16 C/D frag
typedef __attribute__((ext_vector_type(16))) float f32x16;   // 32x32 C/D frag
typedef __attribute__((ext_vector_type(4)))  unsigned int u32x4;

#define MFMA16(a,b,c) __builtin_amdgcn_mfma_f32_16x16x32_bf16(a,b,c,0,0,0)
#define MFMA32(a,b,c) __builtin_amdgcn_mfma_f32_32x32x16_bf16(a,b,c,0,0,0)

// 1/sqrt(64) * log2(e): folded into Q so softmax uses exp2 directly
#define QSCALE 0.18033688011112042f

__device__ __forceinline__ unsigned short f2bf(float f) {
  union { float f; unsigned u; } a; a.f = f;
  unsigned r = a.u + 0x7fffu + ((a.u >> 16) & 1u);   // RNE (inputs are finite)
  return (unsigned short)(r >> 16);
}

// packed RNE f32x2 -> bf16x2 (T12 recipe: no builtin on gfx950, use asm)
__device__ __forceinline__ unsigned cvtpk(float lo, float hi) {
  unsigned r;
  asm("v_cvt_pk_bf16_f32 %0, %1, %2" : "=v"(r) : "v"(lo), "v"(hi));
  return r;
}

__device__ __forceinline__ void gload16(const void* g, void* l) {
  __builtin_amdgcn_global_load_lds(
      (const __attribute__((address_space(1))) void*)g,
      (__attribute__((address_space(3))) void*)l, 16, 0, 0);
}

// ---------------- cast x (f32 -> bf16), 4 elems/thread ----------------
__global__ void cast_f32_bf16(const float* __restrict__ in,
                              unsigned short* __restrict__ out, int n) {
  int i = (blockIdx.x * 256 + threadIdx.x) * 4;
  if (i >= n) return;
  float4 v = *(const float4*)(in + i);
  ushort4 o;
  o.x = f2bf(v.x); o.y = f2bf(v.y); o.z = f2bf(v.z); o.w = f2bf(v.w);
  *(ushort4*)(out + i) = o;
}

// -------- transpose + cast: in[R][Ncols] f32 -> out[Ncols][R] bf16 --------
__global__ void transpose_cast(const float* __restrict__ in,
                               unsigned short* __restrict__ out,
                               int R, int Ncols) {
  __shared__ float tile[32][33];
  int bc = blockIdx.x * 32;
  int br = blockIdx.y * 32;
  int tx = threadIdx.x, ty = threadIdx.y;  // 32 x 8
  #pragma unroll
  for (int i = ty; i < 32; i += 8)
    tile[i][tx] = in[(size_t)(br + i) * Ncols + bc + tx];
  __syncthreads();
  #pragma unroll
  for (int i = ty; i < 32; i += 8)
    out[(size_t)(bc + i) * R + br + tx] = f2bf(tile[tx][i]);
}

// ---------------- 128x128x64 bf16 MFMA GEMM, Bt = B transposed [N][K] ------
template<int MODE>
__global__ __launch_bounds__(256)
void gemm128(const unsigned short* __restrict__ A,    // [M][K] bf16
             const unsigned short* __restrict__ Bt,   // [N][K] bf16
             unsigned short* __restrict__ qo,
             unsigned short* __restrict__ ko,
             unsigned short* __restrict__ vto,
             float* __restrict__ outf) {
  __shared__ short Asl[128 * 64];
  __shared__ short Bsl[128 * 64];
  const int tid  = threadIdx.x;
  const int wid  = tid >> 6, lane = tid & 63;
  const int l15  = lane & 15, l4 = lane >> 4;
  const int tm   = blockIdx.y * 128;
  const int tn   = blockIdx.x * 128;
  const int wm   = (wid >> 1) * 64, wn = (wid & 1) * 64;

  f32x4 acc[4][4] = {};
  const int stoff = wid * 1024 + lane * 16;

  for (int kt = 0; kt < KDIM; kt += 64) {
    __syncthreads();
    #pragma unroll
    for (int ro = 0; ro < 4; ++ro) {
      int off = ro * 4096 + stoff;
      int row = off >> 7;
      int ce  = (off & 127) >> 1;
      gload16(A  + (size_t)(tm + row) * KDIM + kt + ce,
              (char*)Asl + ro * 4096 + wid * 1024);
      gload16(Bt + (size_t)(tn + row) * KDIM + kt + ce,
              (char*)Bsl + ro * 4096 + wid * 1024);
    }
    __syncthreads();

    #pragma unroll
    for (int ks = 0; ks < 2; ++ks) {
      bf16x8 af[4], bfr[4];
      #pragma unroll
      for (int i = 0; i < 4; ++i) {
        af[i]  = *(const bf16x8*)&Asl[(wm + i*16 + l15) * 64 + ks*32 + l4*8];
        bfr[i] = *(const bf16x8*)&Bsl[(wn + i*16 + l15) * 64 + ks*32 + l4*8];
      }
      #pragma unroll
      for (int mi = 0; mi < 4; ++mi)
        #pragma unroll
        for (int ni = 0; ni < 4; ++ni)
          acc[mi][ni] = MFMA16(af[mi], bfr[ni], acc[mi][ni]);
    }
  }

  #pragma unroll
  for (int mi = 0; mi < 4; ++mi) {
    #pragma unroll
    for (int ni = 0; ni < 4; ++ni) {
      #pragma unroll
      for (int r = 0; r < 4; ++r) {
        int m = tm + wm + mi*16 + l4*4 + r;
        int n = tn + wn + ni*16 + l15;
        float val = acc[mi][ni][r];
        if (MODE == 0) {
          int b = m >> 11, t = m & (T_ - 1);
          int which = n >> 10, n1 = n & (C_ - 1);
          int h = n1 >> 6, d = n1 & 63;
          size_t bh = (size_t)(b * H_ + h);
          if (which == 0)      qo[(bh * T_ + t) * D_ + d] = f2bf(val * QSCALE);
          else if (which == 1) ko[(bh * T_ + t) * D_ + d] = f2bf(val);
          else                 vto[(bh * D_ + d) * T_ + t] = f2bf(val);
        } else {
          outf[(size_t)m * C_ + n] = val;
        }
      }
    }
  }
}

// ---------------- causal flash attention: 32x32 all-in-register ------------
// grid (64 bh, 8 PAIRS), block 256 = 4 waves, 32 q-rows/wave.
// Triangular balance: block processes q-tile `pair` AND q-tile `15-pair`
// sequentially -> constant work per block (~17 k-tiles), no drain tail.
// Swapped QK^T AND swapped PV: all softmax state lane-local. No LDS/barriers.
// K-frags software-prefetched one tile ahead; defer-max (T13, THR=8 log2).
__global__ __launch_bounds__(256)
void attn32(const unsigned short* __restrict__ Q,    // [BH][T][D], pre-scaled
            const unsigned short* __restrict__ K,    // [BH][T][D]
            const unsigned short* __restrict__ Vt,   // [BH][D][T]
            unsigned short* __restrict__ Y) {        // [B][T][C] bf16
  const int bh   = blockIdx.x;
  const int pair = blockIdx.y;                            // 0..7
  const int lane = threadIdx.x & 63, w = threadIdx.x >> 6;
  const int l31  = lane & 31, hi = lane >> 5;
  const int b    = bh >> 4, h = bh & 15;

  const unsigned short* Qp = Q  + (size_t)bh * T_ * D_;
  const unsigned short* Kp = K  + (size_t)bh * T_ * D_;
  const unsigned short* Vp = Vt + (size_t)bh * D_ * T_;

  const int NQT = T_ / 128;   // 16 q-tiles of 128 rows

  for (int half = 0; half < 2; ++half) {
    const int qtile = half ? (NQT - 1 - pair) : pair;
    const int q0 = qtile * 128 + w * 32;                  // wave's 32 q-rows

    // Q as B-frag (col=q=l31, contraction d = c*16 + hi*8 + j)
    bf16x8 qf[4];
    #pragma unroll
    for (int c = 0; c < 4; ++c)
      qf[c] = *(const bf16x8*)&Qp[(size_t)(q0 + l31) * D_ + c*16 + hi*8];

    f32x16 acc[2] = {};          // Y^T: col=q=l31, row d = dt*32 + crow(r,hi)
    float m_q = -INFINITY, l_q = 0.f;

    const int nt = (q0 + 31) / 64 + 1;

    // preload K frags for kt=0 (row=k=l31, contraction d = c*16+hi*8+j)
    bf16x8 kfc[2][4];
    #pragma unroll
    for (int kb = 0; kb < 2; ++kb)
      #pragma unroll
      for (int c = 0; c < 4; ++c)
        kfc[kb][c] = *(const bf16x8*)&Kp[(size_t)(kb*32 + l31) * D_ + c*16 + hi*8];

    for (int kt = 0; kt < nt; ++kt) {
      const int k0 = kt * 64;

      // S^T = K Q^T: s2[kb] col=q=l31, row k = k0+kb*32+crow(r,hi)
      f32x16 s2[2] = {};
      __builtin_amdgcn_s_setprio(1);
      #pragma unroll
      for (int c = 0; c < 4; ++c) s2[0] = MFMA32(kfc[0][c], qf[c], s2[0]);
      #pragma unroll
      for (int c = 0; c < 4; ++c) s2[1] = MFMA32(kfc[1][c], qf[c], s2[1]);
      __builtin_amdgcn_s_setprio(0);

      // V^T frags for THIS tile (consumed at PV, ~300cy away)
      bf16x8 va[2][4];
      #pragma unroll
      for (int dt = 0; dt < 2; ++dt)
        #pragma unroll
        for (int s = 0; s < 4; ++s)
          va[dt][s] = *(const bf16x8*)&Vp[(size_t)(dt*32 + l31) * T_ + k0 + s*16 + hi*8];

      // K frags for NEXT tile (consumed at next QK^T, ~600cy away)
      bf16x8 kfn[2][4];
      const bool havenext = (kt + 1 < nt);
      if (havenext) {
        const int k1 = k0 + 64;
        #pragma unroll
        for (int kb = 0; kb < 2; ++kb)
          #pragma unroll
          for (int c = 0; c < 4; ++c)
            kfn[kb][c] = *(const bf16x8*)&Kp[(size_t)(k1 + kb*32 + l31) * D_ + c*16 + hi*8];
      }

      if (kt == nt - 1) {        // diagonal: mask k > q (lane-local compare)
        #pragma unroll
        for (int kb = 0; kb < 2; ++kb)
          #pragma unroll
          for (int r = 0; r < 16; ++r) {
            int krow = k0 + kb*32 + (r&3) + 8*(r>>2) + 4*hi;
            if (krow > q0 + l31) s2[kb][r] = -INFINITY;
          }
      }

      // ---- online softmax, lane-local for q = q0+l31; defer-max (T13)
      float tmax = s2[0][0];
      #pragma unroll
      for (int kb = 0; kb < 2; ++kb)
        #pragma unroll
        for (int r = 0; r < 16; ++r) tmax = fmaxf(tmax, s2[kb][r]);

      if (!__all(tmax <= m_q + 8.0f)) {    // rescale path (incl. first tile)
        float tm2 = fmaxf(tmax, __shfl_xor(tmax, 32, 64));
        float mn  = fmaxf(m_q, tm2);
        float scale = exp2f(m_q - mn);     // Q pre-scaled by log2e
        m_q = mn;
        l_q *= scale;
        #pragma unroll
        for (int r = 0; r < 16; ++r) { acc[0][r] *= scale; acc[1][r] *= scale; }
      }
      // else: keep m_q; P bounded by 2^8, f32 accum has headroom

      float rsum = 0.f;
      #pragma unroll
      for (int kb = 0; kb < 2; ++kb)
        #pragma unroll
        for (int r = 0; r < 16; ++r) {
          float p = exp2f(s2[kb][r] - m_q);
          s2[kb][r] = p;
          rsum += p;
        }
      rsum += __shfl_xor(rsum, 32, 64);
      l_q += rsum;

      // ---- P pack (cvt_pk) + permlane32_swap -> P^T B-frags pb[s]
      // source: s2[kb][r] = P[k = kb*32 + (r&3)+8*(r>>2)+4*hi][q=l31]
      // target: pb[s] word m = P[k = s*16 + hi*8 + 2m + {0,1}][q=l31]
      u32x4 pb[4];
      #pragma unroll
      for (int kb = 0; kb < 2; ++kb)
        #pragma unroll
        for (int ss = 0; ss < 2; ++ss)
          #pragma unroll
          for (int b2 = 0; b2 < 2; ++b2) {
            unsigned ce = cvtpk(s2[kb][8*ss     + 2*b2], s2[kb][8*ss     + 2*b2 + 1]);
            unsigned co = cvtpk(s2[kb][8*ss + 4 + 2*b2], s2[kb][8*ss + 4 + 2*b2 + 1]);
            auto rr = __builtin_amdgcn_permlane32_swap(ce, co, false, false);
            pb[kb*2 + ss][b2]     = rr[0];   // {ce.lo32, co.lo32}
            pb[kb*2 + ss][2 + b2] = rr[1];   // {ce.hi32, co.hi32}
          }

      // ---- Y^T += V^T P^T
      __builtin_amdgcn_s_setprio(1);
      #pragma unroll
      for (int dt = 0; dt < 2; ++dt)
        #pragma unroll
        for (int s = 0; s < 4; ++s)
          acc[dt] = MFMA32(va[dt][s], __builtin_bit_cast(bf16x8, pb[s]), acc[dt]);
      __builtin_amdgcn_s_setprio(0);

      // rotate prefetched K into current
      if (havenext) {
        #pragma unroll
        for (int kb = 0; kb < 2; ++kb)
          #pragma unroll
          for (int c = 0; c < 4; ++c)
            kfc[kb][c] = kfn[kb][c];
      }
    }

    // ---- epilogue: all lane-local; pack 4 consecutive d as 8B stores
    float inv = 1.0f / l_q;
    const int t = q0 + l31;
    unsigned short* Yrow = Y + ((size_t)b * T_ + t) * C_ + h * D_;
    #pragma unroll
    for (int dt = 0; dt < 2; ++dt)
      #pragma unroll
      for (int rg = 0; rg < 4; ++rg) {
        uint2 wv;
        wv.x = cvtpk(acc[dt][rg*4 + 0] * inv, acc[dt][rg*4 + 1] * inv);
        wv.y = cvtpk(acc[dt][rg*4 + 2] * inv, acc[dt][rg*4 + 3] * inv);
        *(uint2*)(Yrow + dt*32 + rg*8 + hi*4) = wv;   // d = dt*32+8rg+4hi+{0..3}
      }
  }
}

// ---------------------------------------------------------------------------
extern "C" void kernel_launch(void* const* d_in, const int* in_sizes, int n_in,
                              void* d_out, int out_size, void* d_ws, size_t ws_size,
                              hipStream_t stream) {
  const float* x      = (const float*)d_in[0];
  const float* w_attn = (const float*)d_in[1];
  const float* w_proj = (const float*)d_in[2];
  float* out = (float*)d_out;

  char* ws = (char*)d_ws;
  size_t off = 0;
  auto alloc = [&](size_t bytes) {
    char* p = ws + off; off += (bytes + 255) & ~(size_t)255; return p;
  };
  unsigned short* xb  = (unsigned short*)alloc((size_t)M_ * C_ * 2);
  unsigned short* wat = (unsigned short*)alloc((size_t)N3 * KDIM * 2);
  unsigned short* wpt = (unsigned short*)alloc((size_t)C_ * C_ * 2);
  unsigned short* qb  = (unsigned short*)alloc((size_t)M_ * C_ * 2);
  unsigned short* kb  = (unsigned short*)alloc((size_t)M_ * C_ * 2);
  unsigned short* vtb = (unsigned short*)alloc((size_t)M_ * C_ * 2);
  unsigned short* yb  = (unsigned short*)alloc((size_t)M_ * C_ * 2);

  cast_f32_bf16<<<dim3(M_ * C_ / 1024), dim3(256), 0, stream>>>(x, xb, M_ * C_);
  transpose_cast<<<dim3(N3 / 32, KDIM / 32), dim3(32, 8), 0, stream>>>(w_attn, wat, KDIM, N3);
  transpose_cast<<<dim3(C_ / 32, C_ / 32), dim3(32, 8), 0, stream>>>(w_proj, wpt, C_, C_);

  gemm128<0><<<dim3(N3 / 128, M_ / 128), dim3(256), 0, stream>>>(xb, wat, qb, kb, vtb, nullptr);
  attn32<<<dim3(B_ * H_, T_ / 256), dim3(256), 0, stream>>>(qb, kb, vtb, yb);
  gemm128<1><<<dim3(C_ / 128, M_ / 128), dim3(256), 0, stream>>>(yb, wpt, nullptr, nullptr, nullptr, out);
}